// Round 16
// baseline (287.458 us; speedup 1.0000x reference)
//
#include <hip/hip_runtime.h>

#define THREADS 256
#define CSH 6          // course bin shift: 64 courses/bin  -> 157 bins
#define USH 12         // user bin shift: 4096 users/bin    -> 123 bins
#define MAXBIN 192

typedef _Float16 half8 __attribute__((ext_vector_type(8)));
typedef _Float16 half4 __attribute__((ext_vector_type(4)));
typedef float floatx4 __attribute__((ext_vector_type(4)));

static __device__ __forceinline__ int imax(int a, int b){ return a > b ? a : b; }
static __device__ __forceinline__ int imin(int a, int b){ return a < b ? a : b; }

// ---------------- merged: phase0 histograms (blocks < chunks) + feature prep (rest) ----------------

__global__ __launch_bounds__(256) void k_p0feat(
    const int* __restrict__ es, const int* __restrict__ ed,
    int* __restrict__ cnt_c, int* __restrict__ cnt_u, int E, int NBC, int NBU, int chunks,
    const float* __restrict__ uemb, const int* __restrict__ uidx,
    const float* __restrict__ ux, _Float16* __restrict__ xu16, int NU,
    const float* __restrict__ cx, const float* __restrict__ cemb,
    const int* __restrict__ cidx, const float* __restrict__ Wc,
    const float* __restrict__ bc, float* __restrict__ xc,
    _Float16* __restrict__ xc16, int NC)
{
    int t = threadIdx.x;
    if ((int)blockIdx.x < chunks){
        __shared__ int hc[MAXBIN], hu[MAXBIN];
        int base = blockIdx.x * 2048 + t;
        if (t < MAXBIN){ hc[t] = 0; hu[t] = 0; }
        __syncthreads();
        #pragma unroll
        for (int k = 0; k < 8; k++){
            int i = base + k * 256;
            if (i < E){
                int s = __builtin_nontemporal_load(&es[i]);
                int d = __builtin_nontemporal_load(&ed[i]);
                atomicAdd(&hc[d >> CSH], 1); atomicAdd(&hu[s >> USH], 1);
            }
        }
        __syncthreads();
        if (t < NBC && hc[t]) atomicAdd(&cnt_c[t], hc[t]);
        if (t < NBU && hu[t]) atomicAdd(&cnt_u[t], hu[t]);
        return;
    }
    int gid = (blockIdx.x - chunks) * 256 + t;
    if (gid < NU){
        int u = gid;
        const float4* er = (const float4*)(uemb + (size_t)uidx[u] * 16);
        float4 e0 = er[0], e1 = er[1], e2 = er[2], e3 = er[3];
        _Float16 h[32];
        h[0]=(_Float16)e0.x; h[1]=(_Float16)e0.y; h[2]=(_Float16)e0.z; h[3]=(_Float16)e0.w;
        h[4]=(_Float16)e1.x; h[5]=(_Float16)e1.y; h[6]=(_Float16)e1.z; h[7]=(_Float16)e1.w;
        h[8]=(_Float16)e2.x; h[9]=(_Float16)e2.y; h[10]=(_Float16)e2.z; h[11]=(_Float16)e2.w;
        h[12]=(_Float16)e3.x; h[13]=(_Float16)e3.y; h[14]=(_Float16)e3.z; h[15]=(_Float16)e3.w;
        const float* xr = ux + (size_t)u * 5;
        h[16]=(_Float16)xr[0]; h[17]=(_Float16)xr[1]; h[18]=(_Float16)xr[2]; h[19]=(_Float16)xr[3]; h[20]=(_Float16)xr[4];
        #pragma unroll
        for (int q = 21; q < 32; q++) h[q] = (_Float16)0.f;
        float4* out = (float4*)(xu16 + (size_t)u * 32);
        const float4* hv = (const float4*)h;
        out[0] = hv[0]; out[1] = hv[1]; out[2] = hv[2]; out[3] = hv[3];
    } else {
        int i = gid - NU;
        if (i >= NC * 32) return;
        int c = i >> 5, f = i & 31;
        float v;
        if (f < 16) v = cemb[cidx[c] * 16 + f];
        else { int o = f - 16; v = bc[o] + cx[c * 2 + 0] * Wc[o * 2 + 0] + cx[c * 2 + 1] * Wc[o * 2 + 1]; }
        xc[i] = v;
        xc16[i] = (_Float16)v;
    }
}

// merged: block 0 = bin-base scan; block 1 = weight prep
__global__ void k_misc(const int* __restrict__ cnt_c, const int* __restrict__ cnt_u,
                       int* __restrict__ base_c, int* __restrict__ cur_c,
                       int* __restrict__ base_u, int* __restrict__ cur_u,
                       int* __restrict__ off_c, int* __restrict__ off_u,
                       int NC, int NU, int NBC, int NBU, int E,
                       const float* __restrict__ Wl, const float* __restrict__ bl,
                       const float* __restrict__ Wr, const float* __restrict__ Wu,
                       const float* __restrict__ bu,
                       const float* __restrict__ Acoef, const float* __restrict__ Bcoef,
                       _Float16* __restrict__ wB1a, _Float16* __restrict__ wB1b,
                       _Float16* __restrict__ wB2, float* __restrict__ whb){
    int t = threadIdx.x;
    if (blockIdx.x == 0){
        if (t == 0){
            int a = 0;
            for (int b = 0; b < NBC; b++){ base_c[b] = a; cur_c[b] = a; a += cnt_c[b]; }
            a = 0;
            for (int b = 0; b < NBU; b++){ base_u[b] = a; cur_u[b] = a; a += cnt_u[b]; }
            off_c[NC] = E; off_u[NU] = E;
        }
        return;
    }
    if (t < 128){
        int nt = t >> 6, l = t & 63;
        int ur = l & 15, kg = l >> 4, o = nt * 16 + ur;
        _Float16* pa = wB1a + (size_t)(nt * 64 + l) * 8;
        _Float16* pb = wB1b + (size_t)(nt * 64 + l) * 8;
        #pragma unroll
        for (int j = 0; j < 8; j++){
            pa[j] = (_Float16)Wl[o * 32 + kg * 8 + j];
            int k = kg * 8 + j;
            float v;
            if (k < 16) v = Wr[o * 32 + k];
            else if (k < 21){
                int pc = k - 16; float s = 0.f;
                for (int m = 0; m < 16; m++) s += Wr[o * 32 + 16 + m] * Wu[m * 5 + pc];
                v = s;
            } else v = 0.f;
            pb[j] = (_Float16)v;
        }
        const float* W = nt ? Bcoef : Acoef;
        _Float16* p2 = wB2 + (size_t)(nt * 64 + l) * 8;
        #pragma unroll
        for (int j = 0; j < 8; j++) p2[j] = (_Float16)W[ur * 32 + kg * 8 + j];
    } else if (t < 160){
        int o = t - 128;
        float s = bl[o];
        for (int m = 0; m < 16; m++) s += Wr[o * 32 + 16 + m] * bu[m];
        whb[o] = s;
    }
}

// phase1 with packed records: course rec = (src<<6)|dstlow6, user rec = (dst<<12)|srclow12
__global__ __launch_bounds__(256) void k_phase1(const int* __restrict__ es, const int* __restrict__ ed,
                                                int* __restrict__ cur_c, int* __restrict__ cur_u,
                                                unsigned* __restrict__ binned_c, unsigned* __restrict__ binned_u,
                                                int E, int NBC, int NBU){
    __shared__ unsigned stc[2048], stu[2048];
    __shared__ unsigned char bc8[2048], bu8[2048];
    __shared__ int hc[MAXBIN], scc[MAXBIN], lcc[MAXBIN], gbc[MAXBIN];
    __shared__ int hu[MAXBIN], scu[MAXBIN], lcu[MAXBIN], gbu[MAXBIN];
    int t = threadIdx.x;
    int base = blockIdx.x * 2048 + t;
    int s[8], d[8];
    #pragma unroll
    for (int k = 0; k < 8; k++){
        int i = base + k * 256;
        if (i < E){ s[k] = __builtin_nontemporal_load(&es[i]); d[k] = __builtin_nontemporal_load(&ed[i]); }
    }
    if (t < MAXBIN){ hc[t] = 0; hu[t] = 0; }
    __syncthreads();
    #pragma unroll
    for (int k = 0; k < 8; k++){
        int i = base + k * 256;
        if (i < E){ atomicAdd(&hc[d[k] >> CSH], 1); atomicAdd(&hu[s[k] >> USH], 1); }
    }
    __syncthreads();
    if (t == 0){ int a = 0; for (int b = 0; b < NBC; b++){ scc[b] = a; a += hc[b]; } }
    if (t == 1){ int a = 0; for (int b = 0; b < NBU; b++){ scu[b] = a; a += hu[b]; } }
    __syncthreads();
    if (t < NBC){ lcc[t] = scc[t]; gbc[t] = atomicAdd(&cur_c[t], hc[t]); }
    if (t < NBU){ lcu[t] = scu[t]; gbu[t] = atomicAdd(&cur_u[t], hu[t]); }
    __syncthreads();
    #pragma unroll
    for (int k = 0; k < 8; k++){
        int i = base + k * 256;
        if (i < E){
            int bc = d[k] >> CSH;
            int p = atomicAdd(&lcc[bc], 1);
            stc[p] = ((unsigned)s[k] << CSH) | ((unsigned)d[k] & ((1u << CSH) - 1));
            bc8[p] = (unsigned char)bc;
            int bu2 = s[k] >> USH;
            int q = atomicAdd(&lcu[bu2], 1);
            stu[q] = ((unsigned)d[k] << USH) | ((unsigned)s[k] & ((1u << USH) - 1));
            bu8[q] = (unsigned char)bu2;
        }
    }
    __syncthreads();
    int nv = imin(2048, E - blockIdx.x * 2048);
    for (int i = t; i < nv; i += 256){
        unsigned e = stc[i]; int b  = bc8[i]; binned_c[gbc[b]  + (i - scc[b])]  = e;
        unsigned f = stu[i]; int b2 = bu8[i]; binned_u[gbu[b2] + (i - scu[b2])] = f;
    }
}

__global__ __launch_bounds__(1024) void k_p2(const unsigned* __restrict__ binned_c, const unsigned* __restrict__ binned_u,
                                             const int* __restrict__ cnt_c, const int* __restrict__ base_c,
                                             const int* __restrict__ cnt_u, const int* __restrict__ base_u,
                                             int* __restrict__ off_c, int* __restrict__ csr_c,
                                             int* __restrict__ off_u, int* __restrict__ csr_u,
                                             int NC, int NU, int NBC){
    __shared__ int lsh[5120];
    int t = threadIdx.x;
    const int CB = 1 << CSH;
    if ((int)blockIdx.x < NBC){
        int b = blockIdx.x;
        int* lh  = lsh;
        int* lof = lsh + CB;
        if (t < CB) lh[t] = 0;
        __syncthreads();
        int n = cnt_c[b], gb = base_c[b];
        const unsigned* src = binned_c + gb;
        for (int i = t; i < n; i += 1024) atomicAdd(&lh[src[i] & (CB - 1)], 1);
        __syncthreads();
        if (t == 0){ int a = gb; for (int c = 0; c < CB; c++){ lof[c] = a; a += lh[c]; } }
        __syncthreads();
        int gc = (b << CSH) + t;
        if (t < CB && gc < NC) off_c[gc] = lof[t];
        __syncthreads();
        for (int i = t; i < n; i += 1024){
            unsigned e = src[i];
            int p = atomicAdd(&lof[e & (CB - 1)], 1);
            csr_c[p] = (int)(e >> CSH);
        }
    } else {
        int b = blockIdx.x - NBC;
        const int UB = 1 << USH;
        int* lh   = lsh;
        int* part = lsh + UB;
        for (int i = t; i < UB; i += 1024) lh[i] = 0;
        __syncthreads();
        int n = cnt_u[b], gb = base_u[b];
        const unsigned* src = binned_u + gb;
        for (int i = t; i < n; i += 1024) atomicAdd(&lh[src[i] & (UB - 1)], 1);
        __syncthreads();
        int ps = lh[t * 4] + lh[t * 4 + 1] + lh[t * 4 + 2] + lh[t * 4 + 3];
        part[t] = ps;
        __syncthreads();
        for (int dd = 1; dd < 1024; dd <<= 1){
            int v = (t >= dd) ? part[t - dd] : 0;
            __syncthreads();
            if (t >= dd) part[t] += v;
            __syncthreads();
        }
        int a2 = gb + (t ? part[t - 1] : 0);
        #pragma unroll
        for (int j = 0; j < 4; j++){ int idx = t * 4 + j; int tmp = lh[idx]; lh[idx] = a2; a2 += tmp; }
        __syncthreads();
        int ub = b << USH;
        for (int i = t; i < UB; i += 1024){ int gu = ub + i; if (gu < NU) off_u[gu] = lh[i]; }
        __syncthreads();
        for (int i = t; i < n; i += 1024){
            unsigned e = src[i];
            int p = atomicAdd(&lh[e & (UB - 1)], 1);
            csr_u[p] = (int)(e >> USH);
        }
    }
}

// ---------------- layer 1 course side (8 gather chains) ----------------

__global__ __launch_bounds__(256) void k_course_l1(
    const int* __restrict__ off_c, const int* __restrict__ csr_c,
    const _Float16* __restrict__ xu16,
    const float* __restrict__ Wu, const float* __restrict__ bu,
    const float* __restrict__ Wl, const float* __restrict__ bl, const float* __restrict__ Wr,
    const float* __restrict__ Acoef /*c2r_Wl*/, const float* __restrict__ Bcoef /*c2e_Wr*/,
    const float* __restrict__ xc,
    _Float16* __restrict__ hc2r16, float* __restrict__ hcWr, int NC)
{
    __shared__ float sWlT[1024], sWrT[1024], sAT[512], sBT[512], sWu[80], sbu[16], sbl[32];
    __shared__ float part[256];
    __shared__ float agg[32], aggx[8], hc[32];
    int t = threadIdx.x;
    for (int i = t; i < 1024; i += 256){ int o = i >> 5, k = i & 31; sWlT[k * 32 + o] = Wl[i]; sWrT[k * 32 + o] = Wr[i]; }
    for (int i = t; i < 512;  i += 256){ int j = i >> 5, o = i & 31; sAT[o * 16 + j] = Acoef[i]; sBT[o * 16 + j] = Bcoef[i]; }
    if (t < 80) sWu[t] = Wu[t];
    if (t < 16) sbu[t] = bu[t];
    if (t < 32) sbl[t] = bl[t];
    __syncthreads();
    int el = t >> 5, f = t & 31;
    for (int c = blockIdx.x; c < NC; c += gridDim.x){
        int lo = off_c[c], hi = off_c[c + 1];
        float acc = 0.f;
        int j = lo + el;
        for (; j + 56 < hi; j += 64){              // 8 independent gather chains
            int s0 = csr_c[j],      s1 = csr_c[j + 8],  s2 = csr_c[j + 16], s3 = csr_c[j + 24];
            int s4 = csr_c[j + 32], s5 = csr_c[j + 40], s6 = csr_c[j + 48], s7 = csr_c[j + 56];
            float v0 = (float)xu16[(size_t)s0 * 32 + f], v1 = (float)xu16[(size_t)s1 * 32 + f];
            float v2 = (float)xu16[(size_t)s2 * 32 + f], v3 = (float)xu16[(size_t)s3 * 32 + f];
            float v4 = (float)xu16[(size_t)s4 * 32 + f], v5 = (float)xu16[(size_t)s5 * 32 + f];
            float v6 = (float)xu16[(size_t)s6 * 32 + f], v7 = (float)xu16[(size_t)s7 * 32 + f];
            acc += ((v0 + v1) + (v2 + v3)) + ((v4 + v5) + (v6 + v7));
        }
        for (; j < hi; j += 8) acc += (float)xu16[(size_t)csr_c[j] * 32 + f];
        part[t] = acc; __syncthreads();
        float inv = 1.f / (float)imax(hi - lo, 1);
        if (el == 0 && f < 21){
            float s2 = part[f];
            #pragma unroll
            for (int k = 1; k < 8; k++) s2 += part[k * 32 + f];
            s2 *= inv;
            if (f < 16) agg[f] = s2; else aggx[f - 16] = s2;
        }
        __syncthreads();
        if (t < 16){
            float d = sbu[t];
            #pragma unroll
            for (int k = 0; k < 5; k++) d += aggx[k] * sWu[t * 5 + k];
            agg[16 + t] = d;
        }
        __syncthreads();
        if (t < 32){
            float h = sbl[t];
            for (int k = 0; k < 32; k++) h += agg[k] * sWlT[k * 32 + t] + xc[c * 32 + k] * sWrT[k * 32 + t];
            hc[t] = fmaxf(h, 0.f);
        }
        __syncthreads();
        if (t < 16){
            float a = 0.f, b = 0.f;
            for (int o = 0; o < 32; o++){ float h = hc[o]; a += h * sAT[o * 16 + t]; b += h * sBT[o * 16 + t]; }
            hc2r16[c * 16 + t] = (_Float16)a; hcWr[c * 16 + t] = b;
        }
        __syncthreads();
    }
}

// ---------------- fused user side, MFMA version (full pk-f16 accum, 8-wide walk) ----------------

__global__ __launch_bounds__(256) void k_user_mfma(
    const int* __restrict__ off_u, const int* __restrict__ csr_u,
    const _Float16* __restrict__ xc16, const _Float16* __restrict__ hc2r16,
    const _Float16* __restrict__ xu16,
    const _Float16* __restrict__ wB1a, const _Float16* __restrict__ wB1b,
    const _Float16* __restrict__ wB2, const float* __restrict__ whb,
    const float* __restrict__ bl2 /*c2r_bl*/,
    _Float16* __restrict__ hu2e, _Float16* __restrict__ ou, int NU)
{
    const int t = threadIdx.x;
    const int w = t >> 6, l = t & 63;
    const int ur = l & 15;
    const int kg = l >> 4;

    half8 b1[2][2], b2[2];
    b1[0][0] = *(const half8*)(wB1a + (size_t)l * 8);
    b1[0][1] = *(const half8*)(wB1a + (size_t)(64 + l) * 8);
    b1[1][0] = *(const half8*)(wB1b + (size_t)l * 8);
    b1[1][1] = *(const half8*)(wB1b + (size_t)(64 + l) * 8);
    b2[0]    = *(const half8*)(wB2  + (size_t)l * 8);
    b2[1]    = *(const half8*)(wB2  + (size_t)(64 + l) * 8);
    float hbias[2] = { whb[ur], whb[16 + ur] };
    const float bl2v = bl2[ur];

    __shared__ float lds_all[4][16 * 36 + 16 * 20];
    float* hl  = lds_all[w];
    float* b0l = lds_all[w] + 16 * 36;

    const int stride = gridDim.x * 64;
    for (int u0 = blockIdx.x * 64 + w * 16; u0 < NU; u0 += stride){
        int u = u0 + ur;
        int lo = 0, n = 0;
        if (u < NU){ lo = off_u[u]; n = off_u[u + 1] - lo; }
        half8 axv;
        half4 apv;
        #pragma unroll
        for (int q = 0; q < 8; q++) axv[q] = (_Float16)0.f;
        #pragma unroll
        for (int q = 0; q < 4; q++) apv[q] = (_Float16)0.f;
        int j = 0;
        while (__any(j < n)){
            int dd[8];
            #pragma unroll
            for (int k = 0; k < 8; k++) dd[k] = (j + k < n) ? csr_u[lo + j + k] : -1;
            #pragma unroll
            for (int k = 0; k < 8; k++){
                if (dd[k] >= 0){
                    axv += *(const half8*)(xc16 + (size_t)dd[k] * 32 + kg * 8);   // v_pk_add_f16
                    apv += *(const half4*)(hc2r16 + (size_t)dd[k] * 16 + kg * 4); // v_pk_add_f16
                }
            }
            j += 8;
        }
        float inv = 1.f / (float)imax(n, 1);
        half8 a1, a2;
        #pragma unroll
        for (int q = 0; q < 8; q++) a1[q] = (_Float16)((float)axv[q] * inv);
        #pragma unroll
        for (int q = 0; q < 8; q++) a2[q] = (_Float16)0.f;
        if (u < NU) a2 = *(const half8*)(xu16 + (size_t)u * 32 + kg * 8);
        floatx4 c1[2];
        #pragma unroll
        for (int nt = 0; nt < 2; nt++){
            floatx4 c = {hbias[nt], hbias[nt], hbias[nt], hbias[nt]};
            c = __builtin_amdgcn_mfma_f32_16x16x32_f16(a1, b1[0][nt], c, 0, 0, 0);
            c = __builtin_amdgcn_mfma_f32_16x16x32_f16(a2, b1[1][nt], c, 0, 0, 0);
            c1[nt] = c;
        }
        asm volatile("s_waitcnt lgkmcnt(0)" ::: "memory");
        #pragma unroll
        for (int nt = 0; nt < 2; nt++)
            #pragma unroll
            for (int r = 0; r < 4; r++)
                hl[(kg * 4 + r) * 36 + nt * 16 + ur] = fmaxf(c1[nt][r], 0.f);
        #pragma unroll
        for (int q = 0; q < 4; q++) b0l[ur * 20 + kg * 4 + q] = (float)apv[q] * inv;
        asm volatile("s_waitcnt lgkmcnt(0)" ::: "memory");
        half8 ah;
        {
            const float* hp = hl + ur * 36 + kg * 8;
            #pragma unroll
            for (int q = 0; q < 8; q++) ah[q] = (_Float16)hp[q];
        }
        floatx4 c20 = {0.f, 0.f, 0.f, 0.f};
        c20 = __builtin_amdgcn_mfma_f32_16x16x32_f16(ah, b2[0], c20, 0, 0, 0);
        floatx4 c21 = {bl2v, bl2v, bl2v, bl2v};
        c21 = __builtin_amdgcn_mfma_f32_16x16x32_f16(ah, b2[1], c21, 0, 0, 0);
        #pragma unroll
        for (int r = 0; r < 4; r++){
            int urow = kg * 4 + r;
            int ug = u0 + urow;
            if (ug < NU){
                hu2e[(size_t)ug * 16 + ur] = (_Float16)c20[r];
                ou[(size_t)ug * 16 + ur]   = (_Float16)(c21[r] + b0l[urow * 20 + ur]);
            }
        }
    }
}

// ---------------- layer 2 course side (fp16 hu2e gather, 8 chains) ----------------

__global__ __launch_bounds__(256) void k_course_l2(
    const int* __restrict__ off_c, const int* __restrict__ csr_c,
    const _Float16* __restrict__ hu2e, const float* __restrict__ bl2,
    const float* __restrict__ hcWr, float* __restrict__ oc, int NC)
{
    __shared__ float part[256];
    int t = threadIdx.x; int el = t >> 4, f = t & 15;
    for (int c = blockIdx.x; c < NC; c += gridDim.x){
        int lo = off_c[c], hi = off_c[c + 1];
        float acc = 0.f;
        int j = lo + el;
        for (; j + 112 < hi; j += 128){            // 8 independent gather chains
            int s0 = csr_c[j],      s1 = csr_c[j + 16], s2 = csr_c[j + 32],  s3 = csr_c[j + 48];
            int s4 = csr_c[j + 64], s5 = csr_c[j + 80], s6 = csr_c[j + 96],  s7 = csr_c[j + 112];
            float v0 = (float)hu2e[(size_t)s0 * 16 + f], v1 = (float)hu2e[(size_t)s1 * 16 + f];
            float v2 = (float)hu2e[(size_t)s2 * 16 + f], v3 = (float)hu2e[(size_t)s3 * 16 + f];
            float v4 = (float)hu2e[(size_t)s4 * 16 + f], v5 = (float)hu2e[(size_t)s5 * 16 + f];
            float v6 = (float)hu2e[(size_t)s6 * 16 + f], v7 = (float)hu2e[(size_t)s7 * 16 + f];
            acc += ((v0 + v1) + (v2 + v3)) + ((v4 + v5) + (v6 + v7));
        }
        for (; j < hi; j += 16) acc += (float)hu2e[(size_t)csr_c[j] * 16 + f];
        part[t] = acc; __syncthreads();
        if (el == 0){
            float s = part[f];
            #pragma unroll
            for (int k = 1; k < 16; k++) s += part[k * 16 + f];
            oc[c * 16 + f] = s / (float)imax(hi - lo, 1) + bl2[f] + hcWr[c * 16 + f];
        }
        __syncthreads();
    }
}

// ---------------- decode (fp16 ou gather) ----------------

__global__ void k_decode(const int* __restrict__ ls, const int* __restrict__ ld,
                         const _Float16* __restrict__ ou, const float* __restrict__ oc,
                         float* __restrict__ out, int L){
    int gt = blockIdx.x * blockDim.x + threadIdx.x;
    int l = gt >> 2, q = gt & 3;
    if (l >= L) return;
    int a = ls[l], b = ld[l];
    half4 va = *(const half4*)(ou + (size_t)a * 16 + q * 4);
    float4 vb = ((const float4*)(oc + (size_t)b * 16))[q];
    float s = (float)va[0] * vb.x + (float)va[1] * vb.y + (float)va[2] * vb.z + (float)va[3] * vb.w;
    s += __shfl_xor(s, 1);
    s += __shfl_xor(s, 2);
    if (q == 0) out[l] = s;
}

// ---------------- launcher ----------------

extern "C" void kernel_launch(void* const* d_in, const int* in_sizes, int n_in,
                              void* d_out, int out_size, void* d_ws, size_t ws_size,
                              hipStream_t stream)
{
    const float* user_x       = (const float*)d_in[0];
    const float* course_x     = (const float*)d_in[1];
    const float* user_embed   = (const float*)d_in[2];
    const float* course_embed = (const float*)d_in[3];
    const float* Wu = (const float*)d_in[4];
    const float* bu = (const float*)d_in[5];
    const float* Wc = (const float*)d_in[6];
    const float* bc = (const float*)d_in[7];
    const float* c1e_Wl = (const float*)d_in[8];
    const float* c1e_bl = (const float*)d_in[9];
    const float* c1e_Wr = (const float*)d_in[10];
    const float* c1r_Wl = (const float*)d_in[11];
    const float* c1r_bl = (const float*)d_in[12];
    const float* c1r_Wr = (const float*)d_in[13];
    const float* c2e_Wl = (const float*)d_in[14];
    const float* c2e_bl = (const float*)d_in[15];
    const float* c2e_Wr = (const float*)d_in[16];
    const float* c2r_Wl = (const float*)d_in[17];
    const float* c2r_bl = (const float*)d_in[18];
    const float* c2r_Wr = (const float*)d_in[19];
    const int* uidx      = (const int*)d_in[20];
    const int* cidx      = (const int*)d_in[21];
    const int* edge_src  = (const int*)d_in[22];
    const int* edge_dst  = (const int*)d_in[23];
    const int* label_src = (const int*)d_in[24];
    const int* label_dst = (const int*)d_in[25];
    const int NU = in_sizes[20], NC = in_sizes[21], E = in_sizes[22], L = in_sizes[24];
    const int NBC = (NC + (1 << CSH) - 1) >> CSH;
    const int NBU = (NU + (1 << USH) - 1) >> USH;

    char* ws = (char*)d_ws;
    size_t woff = 0;
    auto alloc = [&](size_t bytes) -> char* {
        char* p = ws + woff;
        woff = (woff + bytes + 255) & ~(size_t)255;
        return p;
    };
    int*   off_u = (int*)  alloc((size_t)(NU + 1) * 4);
    int*   off_c = (int*)  alloc((size_t)(NC + 1) * 4);
    int*   csr_c = (int*)  alloc((size_t)E * 4);
    int*   csr_u = (int*)  alloc((size_t)E * 4);
    float* xc    = (float*)alloc((size_t)NC * 32 * 4);
    _Float16* xc16 = (_Float16*)alloc((size_t)NC * 32 * 2);
    _Float16* hc2r16 = (_Float16*)alloc((size_t)NC * 16 * 2);
    float* hcWr  = (float*)alloc((size_t)NC * 16 * 4);
    _Float16* hu2e = (_Float16*)alloc((size_t)NU * 16 * 2);  // 16MB; binned_c aliases (E*4 = 8MB)
    _Float16* ou   = (_Float16*)alloc((size_t)NU * 16 * 2);  // 16MB; binned_u aliases (E*4 = 8MB)
    float* occ   = (float*)alloc((size_t)NC * 16 * 4);
    _Float16* xu16 = (_Float16*)alloc((size_t)NU * 32 * 2);
    _Float16* wB1a = (_Float16*)alloc(1024 * 2);
    _Float16* wB1b = (_Float16*)alloc(1024 * 2);
    _Float16* wB2  = (_Float16*)alloc(1024 * 2);
    float* whb     = (float*)alloc(32 * 4);
    int*   cnt_c  = (int*) alloc(MAXBIN * 4);
    int*   cnt_u  = (int*) alloc(MAXBIN * 4);
    int*   base_c = (int*) alloc(MAXBIN * 4);
    int*   base_u = (int*) alloc(MAXBIN * 4);
    int*   cur_c  = (int*) alloc(MAXBIN * 4);
    int*   cur_u  = (int*) alloc(MAXBIN * 4);
    unsigned* binned_c = (unsigned*)hu2e;
    unsigned* binned_u = (unsigned*)ou;
    (void)ws_size; (void)n_in; (void)out_size;

    int chunks = (E + 2047) / 2048;
    int featblocks = (NU + NC * 32 + 255) / 256;

    hipMemsetAsync(cnt_c, 0, 2 * MAXBIN * 4, stream);   // cnt_c and cnt_u are adjacent
    k_p0feat<<<chunks + featblocks, 256, 0, stream>>>(edge_src, edge_dst, cnt_c, cnt_u, E, NBC, NBU, chunks,
                                                      user_embed, uidx, user_x, xu16, NU,
                                                      course_x, course_embed, cidx, Wc, bc, xc, xc16, NC);
    k_misc<<<2, 256, 0, stream>>>(cnt_c, cnt_u, base_c, cur_c, base_u, cur_u, off_c, off_u,
                                  NC, NU, NBC, NBU, E,
                                  c1r_Wl, c1r_bl, c1r_Wr, Wu, bu, c2e_Wl, c2r_Wr, wB1a, wB1b, wB2, whb);
    k_phase1<<<chunks, 256, 0, stream>>>(edge_src, edge_dst, cur_c, cur_u, binned_c, binned_u, E, NBC, NBU);
    k_p2<<<NBC + NBU, 1024, 0, stream>>>(binned_c, binned_u, cnt_c, base_c, cnt_u, base_u,
                                         off_c, csr_c, off_u, csr_u, NC, NU, NBC);
    k_course_l1<<<2048, 256, 0, stream>>>(off_c, csr_c, xu16, Wu, bu,
                                          c1e_Wl, c1e_bl, c1e_Wr, c2r_Wl, c2e_Wr, xc, hc2r16, hcWr, NC);
    k_user_mfma<<<2048, 256, 0, stream>>>(off_u, csr_u, xc16, hc2r16, xu16,
                                          wB1a, wB1b, wB2, whb, c2r_bl, hu2e, ou, NU);
    k_course_l2<<<2048, 256, 0, stream>>>(off_c, csr_c, hu2e, c2e_bl, hcWr, occ, NC);
    k_decode<<<(unsigned)(((size_t)L * 4 + 255) / 256), 256, 0, stream>>>(label_src, label_dst, ou, occ, (float*)d_out, L);
}

// Round 17
// 278.845 us; speedup vs baseline: 1.0309x; 1.0309x over previous
//
#include <hip/hip_runtime.h>

#define THREADS 256
#define CSH 6          // course bin shift: 64 courses/bin  -> 157 bins
#define USH 12         // user bin shift: 4096 users/bin    -> 123 bins
#define MAXBIN 192

typedef _Float16 half8 __attribute__((ext_vector_type(8)));
typedef _Float16 half4 __attribute__((ext_vector_type(4)));
typedef float floatx4 __attribute__((ext_vector_type(4)));

static __device__ __forceinline__ int imax(int a, int b){ return a > b ? a : b; }
static __device__ __forceinline__ int imin(int a, int b){ return a < b ? a : b; }

// ---------------- merged: phase0 histograms (blocks < chunks) + feature prep (rest) ----------------

__global__ __launch_bounds__(256) void k_p0feat(
    const int* __restrict__ es, const int* __restrict__ ed,
    int* __restrict__ cnt_c, int* __restrict__ cnt_u, int E, int NBC, int NBU, int chunks,
    const float* __restrict__ uemb, const int* __restrict__ uidx,
    const float* __restrict__ ux, _Float16* __restrict__ xu16, int NU,
    const float* __restrict__ cx, const float* __restrict__ cemb,
    const int* __restrict__ cidx, const float* __restrict__ Wc,
    const float* __restrict__ bc, float* __restrict__ xc,
    _Float16* __restrict__ xc16, int NC)
{
    int t = threadIdx.x;
    if ((int)blockIdx.x < chunks){
        __shared__ int hc[MAXBIN], hu[MAXBIN];
        int base = blockIdx.x * 2048 + t;
        if (t < MAXBIN){ hc[t] = 0; hu[t] = 0; }
        __syncthreads();
        #pragma unroll
        for (int k = 0; k < 8; k++){
            int i = base + k * 256;
            if (i < E){
                int s = __builtin_nontemporal_load(&es[i]);
                int d = __builtin_nontemporal_load(&ed[i]);
                atomicAdd(&hc[d >> CSH], 1); atomicAdd(&hu[s >> USH], 1);
            }
        }
        __syncthreads();
        if (t < NBC && hc[t]) atomicAdd(&cnt_c[t], hc[t]);
        if (t < NBU && hu[t]) atomicAdd(&cnt_u[t], hu[t]);
        return;
    }
    int gid = (blockIdx.x - chunks) * 256 + t;
    if (gid < NU){
        int u = gid;
        const float4* er = (const float4*)(uemb + (size_t)uidx[u] * 16);
        float4 e0 = er[0], e1 = er[1], e2 = er[2], e3 = er[3];
        _Float16 h[32];
        h[0]=(_Float16)e0.x; h[1]=(_Float16)e0.y; h[2]=(_Float16)e0.z; h[3]=(_Float16)e0.w;
        h[4]=(_Float16)e1.x; h[5]=(_Float16)e1.y; h[6]=(_Float16)e1.z; h[7]=(_Float16)e1.w;
        h[8]=(_Float16)e2.x; h[9]=(_Float16)e2.y; h[10]=(_Float16)e2.z; h[11]=(_Float16)e2.w;
        h[12]=(_Float16)e3.x; h[13]=(_Float16)e3.y; h[14]=(_Float16)e3.z; h[15]=(_Float16)e3.w;
        const float* xr = ux + (size_t)u * 5;
        h[16]=(_Float16)xr[0]; h[17]=(_Float16)xr[1]; h[18]=(_Float16)xr[2]; h[19]=(_Float16)xr[3]; h[20]=(_Float16)xr[4];
        #pragma unroll
        for (int q = 21; q < 32; q++) h[q] = (_Float16)0.f;
        float4* out = (float4*)(xu16 + (size_t)u * 32);
        const float4* hv = (const float4*)h;
        out[0] = hv[0]; out[1] = hv[1]; out[2] = hv[2]; out[3] = hv[3];
    } else {
        int i = gid - NU;
        if (i >= NC * 32) return;
        int c = i >> 5, f = i & 31;
        float v;
        if (f < 16) v = cemb[cidx[c] * 16 + f];
        else { int o = f - 16; v = bc[o] + cx[c * 2 + 0] * Wc[o * 2 + 0] + cx[c * 2 + 1] * Wc[o * 2 + 1]; }
        xc[i] = v;
        xc16[i] = (_Float16)v;
    }
}

// merged: block 0 = bin-base scan; block 1 = weight prep
__global__ void k_misc(const int* __restrict__ cnt_c, const int* __restrict__ cnt_u,
                       int* __restrict__ base_c, int* __restrict__ cur_c,
                       int* __restrict__ base_u, int* __restrict__ cur_u,
                       int* __restrict__ off_c, int* __restrict__ off_u,
                       int NC, int NU, int NBC, int NBU, int E,
                       const float* __restrict__ Wl, const float* __restrict__ bl,
                       const float* __restrict__ Wr, const float* __restrict__ Wu,
                       const float* __restrict__ bu,
                       const float* __restrict__ Acoef, const float* __restrict__ Bcoef,
                       _Float16* __restrict__ wB1a, _Float16* __restrict__ wB1b,
                       _Float16* __restrict__ wB2, float* __restrict__ whb){
    int t = threadIdx.x;
    if (blockIdx.x == 0){
        if (t == 0){
            int a = 0;
            for (int b = 0; b < NBC; b++){ base_c[b] = a; cur_c[b] = a; a += cnt_c[b]; }
            a = 0;
            for (int b = 0; b < NBU; b++){ base_u[b] = a; cur_u[b] = a; a += cnt_u[b]; }
            off_c[NC] = E; off_u[NU] = E;
        }
        return;
    }
    if (t < 128){
        int nt = t >> 6, l = t & 63;
        int ur = l & 15, kg = l >> 4, o = nt * 16 + ur;
        _Float16* pa = wB1a + (size_t)(nt * 64 + l) * 8;
        _Float16* pb = wB1b + (size_t)(nt * 64 + l) * 8;
        #pragma unroll
        for (int j = 0; j < 8; j++){
            pa[j] = (_Float16)Wl[o * 32 + kg * 8 + j];
            int k = kg * 8 + j;
            float v;
            if (k < 16) v = Wr[o * 32 + k];
            else if (k < 21){
                int pc = k - 16; float s = 0.f;
                for (int m = 0; m < 16; m++) s += Wr[o * 32 + 16 + m] * Wu[m * 5 + pc];
                v = s;
            } else v = 0.f;
            pb[j] = (_Float16)v;
        }
        const float* W = nt ? Bcoef : Acoef;
        _Float16* p2 = wB2 + (size_t)(nt * 64 + l) * 8;
        #pragma unroll
        for (int j = 0; j < 8; j++) p2[j] = (_Float16)W[ur * 32 + kg * 8 + j];
    } else if (t < 160){
        int o = t - 128;
        float s = bl[o];
        for (int m = 0; m < 16; m++) s += Wr[o * 32 + 16 + m] * bu[m];
        whb[o] = s;
    }
}

// phase1 with packed records: course rec = (src<<6)|dstlow6, user rec = (dst<<12)|srclow12
__global__ __launch_bounds__(256) void k_phase1(const int* __restrict__ es, const int* __restrict__ ed,
                                                int* __restrict__ cur_c, int* __restrict__ cur_u,
                                                unsigned* __restrict__ binned_c, unsigned* __restrict__ binned_u,
                                                int E, int NBC, int NBU){
    __shared__ unsigned stc[2048], stu[2048];
    __shared__ unsigned char bc8[2048], bu8[2048];
    __shared__ int hc[MAXBIN], scc[MAXBIN], lcc[MAXBIN], gbc[MAXBIN];
    __shared__ int hu[MAXBIN], scu[MAXBIN], lcu[MAXBIN], gbu[MAXBIN];
    int t = threadIdx.x;
    int base = blockIdx.x * 2048 + t;
    int s[8], d[8];
    #pragma unroll
    for (int k = 0; k < 8; k++){
        int i = base + k * 256;
        if (i < E){ s[k] = __builtin_nontemporal_load(&es[i]); d[k] = __builtin_nontemporal_load(&ed[i]); }
    }
    if (t < MAXBIN){ hc[t] = 0; hu[t] = 0; }
    __syncthreads();
    #pragma unroll
    for (int k = 0; k < 8; k++){
        int i = base + k * 256;
        if (i < E){ atomicAdd(&hc[d[k] >> CSH], 1); atomicAdd(&hu[s[k] >> USH], 1); }
    }
    __syncthreads();
    if (t == 0){ int a = 0; for (int b = 0; b < NBC; b++){ scc[b] = a; a += hc[b]; } }
    if (t == 1){ int a = 0; for (int b = 0; b < NBU; b++){ scu[b] = a; a += hu[b]; } }
    __syncthreads();
    if (t < NBC){ lcc[t] = scc[t]; gbc[t] = atomicAdd(&cur_c[t], hc[t]); }
    if (t < NBU){ lcu[t] = scu[t]; gbu[t] = atomicAdd(&cur_u[t], hu[t]); }
    __syncthreads();
    #pragma unroll
    for (int k = 0; k < 8; k++){
        int i = base + k * 256;
        if (i < E){
            int bc = d[k] >> CSH;
            int p = atomicAdd(&lcc[bc], 1);
            stc[p] = ((unsigned)s[k] << CSH) | ((unsigned)d[k] & ((1u << CSH) - 1));
            bc8[p] = (unsigned char)bc;
            int bu2 = s[k] >> USH;
            int q = atomicAdd(&lcu[bu2], 1);
            stu[q] = ((unsigned)d[k] << USH) | ((unsigned)s[k] & ((1u << USH) - 1));
            bu8[q] = (unsigned char)bu2;
        }
    }
    __syncthreads();
    int nv = imin(2048, E - blockIdx.x * 2048);
    for (int i = t; i < nv; i += 256){
        unsigned e = stc[i]; int b  = bc8[i]; binned_c[gbc[b]  + (i - scc[b])]  = e;
        unsigned f = stu[i]; int b2 = bu8[i]; binned_u[gbu[b2] + (i - scu[b2])] = f;
    }
}

__global__ __launch_bounds__(1024) void k_p2(const unsigned* __restrict__ binned_c, const unsigned* __restrict__ binned_u,
                                             const int* __restrict__ cnt_c, const int* __restrict__ base_c,
                                             const int* __restrict__ cnt_u, const int* __restrict__ base_u,
                                             int* __restrict__ off_c, int* __restrict__ csr_c,
                                             int* __restrict__ off_u, int* __restrict__ csr_u,
                                             int NC, int NU, int NBC){
    __shared__ int lsh[5120];
    int t = threadIdx.x;
    const int CB = 1 << CSH;
    if ((int)blockIdx.x < NBC){
        int b = blockIdx.x;
        int* lh  = lsh;
        int* lof = lsh + CB;
        if (t < CB) lh[t] = 0;
        __syncthreads();
        int n = cnt_c[b], gb = base_c[b];
        const unsigned* src = binned_c + gb;
        for (int i = t; i < n; i += 1024) atomicAdd(&lh[src[i] & (CB - 1)], 1);
        __syncthreads();
        if (t == 0){ int a = gb; for (int c = 0; c < CB; c++){ lof[c] = a; a += lh[c]; } }
        __syncthreads();
        int gc = (b << CSH) + t;
        if (t < CB && gc < NC) off_c[gc] = lof[t];
        __syncthreads();
        for (int i = t; i < n; i += 1024){
            unsigned e = src[i];
            int p = atomicAdd(&lof[e & (CB - 1)], 1);
            csr_c[p] = (int)(e >> CSH);
        }
    } else {
        int b = blockIdx.x - NBC;
        const int UB = 1 << USH;
        int* lh   = lsh;
        int* part = lsh + UB;
        for (int i = t; i < UB; i += 1024) lh[i] = 0;
        __syncthreads();
        int n = cnt_u[b], gb = base_u[b];
        const unsigned* src = binned_u + gb;
        for (int i = t; i < n; i += 1024) atomicAdd(&lh[src[i] & (UB - 1)], 1);
        __syncthreads();
        int ps = lh[t * 4] + lh[t * 4 + 1] + lh[t * 4 + 2] + lh[t * 4 + 3];
        part[t] = ps;
        __syncthreads();
        for (int dd = 1; dd < 1024; dd <<= 1){
            int v = (t >= dd) ? part[t - dd] : 0;
            __syncthreads();
            if (t >= dd) part[t] += v;
            __syncthreads();
        }
        int a2 = gb + (t ? part[t - 1] : 0);
        #pragma unroll
        for (int j = 0; j < 4; j++){ int idx = t * 4 + j; int tmp = lh[idx]; lh[idx] = a2; a2 += tmp; }
        __syncthreads();
        int ub = b << USH;
        for (int i = t; i < UB; i += 1024){ int gu = ub + i; if (gu < NU) off_u[gu] = lh[i]; }
        __syncthreads();
        for (int i = t; i < n; i += 1024){
            unsigned e = src[i];
            int p = atomicAdd(&lh[e & (UB - 1)], 1);
            csr_u[p] = (int)(e >> USH);
        }
    }
}

// ---------------- layer 1 course side (8 gather chains) ----------------

__global__ __launch_bounds__(256) void k_course_l1(
    const int* __restrict__ off_c, const int* __restrict__ csr_c,
    const _Float16* __restrict__ xu16,
    const float* __restrict__ Wu, const float* __restrict__ bu,
    const float* __restrict__ Wl, const float* __restrict__ bl, const float* __restrict__ Wr,
    const float* __restrict__ Acoef /*c2r_Wl*/, const float* __restrict__ Bcoef /*c2e_Wr*/,
    const float* __restrict__ xc,
    _Float16* __restrict__ hc2r16, float* __restrict__ hcWr, int NC)
{
    __shared__ float sWlT[1024], sWrT[1024], sAT[512], sBT[512], sWu[80], sbu[16], sbl[32];
    __shared__ float part[256];
    __shared__ float agg[32], aggx[8], hc[32];
    int t = threadIdx.x;
    for (int i = t; i < 1024; i += 256){ int o = i >> 5, k = i & 31; sWlT[k * 32 + o] = Wl[i]; sWrT[k * 32 + o] = Wr[i]; }
    for (int i = t; i < 512;  i += 256){ int j = i >> 5, o = i & 31; sAT[o * 16 + j] = Acoef[i]; sBT[o * 16 + j] = Bcoef[i]; }
    if (t < 80) sWu[t] = Wu[t];
    if (t < 16) sbu[t] = bu[t];
    if (t < 32) sbl[t] = bl[t];
    __syncthreads();
    int el = t >> 5, f = t & 31;
    for (int c = blockIdx.x; c < NC; c += gridDim.x){
        int lo = off_c[c], hi = off_c[c + 1];
        float acc = 0.f;
        int j = lo + el;
        for (; j + 56 < hi; j += 64){              // 8 independent gather chains
            int s0 = csr_c[j],      s1 = csr_c[j + 8],  s2 = csr_c[j + 16], s3 = csr_c[j + 24];
            int s4 = csr_c[j + 32], s5 = csr_c[j + 40], s6 = csr_c[j + 48], s7 = csr_c[j + 56];
            float v0 = (float)xu16[(size_t)s0 * 32 + f], v1 = (float)xu16[(size_t)s1 * 32 + f];
            float v2 = (float)xu16[(size_t)s2 * 32 + f], v3 = (float)xu16[(size_t)s3 * 32 + f];
            float v4 = (float)xu16[(size_t)s4 * 32 + f], v5 = (float)xu16[(size_t)s5 * 32 + f];
            float v6 = (float)xu16[(size_t)s6 * 32 + f], v7 = (float)xu16[(size_t)s7 * 32 + f];
            acc += ((v0 + v1) + (v2 + v3)) + ((v4 + v5) + (v6 + v7));
        }
        for (; j < hi; j += 8) acc += (float)xu16[(size_t)csr_c[j] * 32 + f];
        part[t] = acc; __syncthreads();
        float inv = 1.f / (float)imax(hi - lo, 1);
        if (el == 0 && f < 21){
            float s2 = part[f];
            #pragma unroll
            for (int k = 1; k < 8; k++) s2 += part[k * 32 + f];
            s2 *= inv;
            if (f < 16) agg[f] = s2; else aggx[f - 16] = s2;
        }
        __syncthreads();
        if (t < 16){
            float d = sbu[t];
            #pragma unroll
            for (int k = 0; k < 5; k++) d += aggx[k] * sWu[t * 5 + k];
            agg[16 + t] = d;
        }
        __syncthreads();
        if (t < 32){
            float h = sbl[t];
            for (int k = 0; k < 32; k++) h += agg[k] * sWlT[k * 32 + t] + xc[c * 32 + k] * sWrT[k * 32 + t];
            hc[t] = fmaxf(h, 0.f);
        }
        __syncthreads();
        if (t < 16){
            float a = 0.f, b = 0.f;
            for (int o = 0; o < 32; o++){ float h = hc[o]; a += h * sAT[o * 16 + t]; b += h * sBT[o * 16 + t]; }
            hc2r16[c * 16 + t] = (_Float16)a; hcWr[c * 16 + t] = b;
        }
        __syncthreads();
    }
}

// ---------------- fused user side, MFMA version (pk-f16 xc accum, fp32 p4, 8-wide walk) ----------------

__global__ __launch_bounds__(256) void k_user_mfma(
    const int* __restrict__ off_u, const int* __restrict__ csr_u,
    const _Float16* __restrict__ xc16, const _Float16* __restrict__ hc2r16,
    const _Float16* __restrict__ xu16,
    const _Float16* __restrict__ wB1a, const _Float16* __restrict__ wB1b,
    const _Float16* __restrict__ wB2, const float* __restrict__ whb,
    const float* __restrict__ bl2 /*c2r_bl*/,
    _Float16* __restrict__ hu2e, _Float16* __restrict__ ou, int NU)
{
    const int t = threadIdx.x;
    const int w = t >> 6, l = t & 63;
    const int ur = l & 15;
    const int kg = l >> 4;

    half8 b1[2][2], b2[2];
    b1[0][0] = *(const half8*)(wB1a + (size_t)l * 8);
    b1[0][1] = *(const half8*)(wB1a + (size_t)(64 + l) * 8);
    b1[1][0] = *(const half8*)(wB1b + (size_t)l * 8);
    b1[1][1] = *(const half8*)(wB1b + (size_t)(64 + l) * 8);
    b2[0]    = *(const half8*)(wB2  + (size_t)l * 8);
    b2[1]    = *(const half8*)(wB2  + (size_t)(64 + l) * 8);
    float hbias[2] = { whb[ur], whb[16 + ur] };
    const float bl2v = bl2[ur];

    __shared__ float lds_all[4][16 * 36 + 16 * 20];
    float* hl  = lds_all[w];
    float* b0l = lds_all[w] + 16 * 36;

    const int stride = gridDim.x * 64;
    for (int u0 = blockIdx.x * 64 + w * 16; u0 < NU; u0 += stride){
        int u = u0 + ur;
        int lo = 0, n = 0;
        if (u < NU){ lo = off_u[u]; n = off_u[u + 1] - lo; }
        half8 axv;
        #pragma unroll
        for (int q = 0; q < 8; q++) axv[q] = (_Float16)0.f;
        float p4[4] = {0,0,0,0};
        int j = 0;
        while (__any(j < n)){
            int dd[8];
            #pragma unroll
            for (int k = 0; k < 8; k++) dd[k] = (j + k < n) ? csr_u[lo + j + k] : -1;
            #pragma unroll
            for (int k = 0; k < 8; k++){
                if (dd[k] >= 0){
                    axv += *(const half8*)(xc16 + (size_t)dd[k] * 32 + kg * 8);
                    half4 hv = *(const half4*)(hc2r16 + (size_t)dd[k] * 16 + kg * 4);
                    #pragma unroll
                    for (int q = 0; q < 4; q++) p4[q] += (float)hv[q];
                }
            }
            j += 8;
        }
        float inv = 1.f / (float)imax(n, 1);
        half8 a1, a2;
        #pragma unroll
        for (int q = 0; q < 8; q++) a1[q] = (_Float16)((float)axv[q] * inv);
        #pragma unroll
        for (int q = 0; q < 8; q++) a2[q] = (_Float16)0.f;
        if (u < NU) a2 = *(const half8*)(xu16 + (size_t)u * 32 + kg * 8);
        floatx4 c1[2];
        #pragma unroll
        for (int nt = 0; nt < 2; nt++){
            floatx4 c = {hbias[nt], hbias[nt], hbias[nt], hbias[nt]};
            c = __builtin_amdgcn_mfma_f32_16x16x32_f16(a1, b1[0][nt], c, 0, 0, 0);
            c = __builtin_amdgcn_mfma_f32_16x16x32_f16(a2, b1[1][nt], c, 0, 0, 0);
            c1[nt] = c;
        }
        asm volatile("s_waitcnt lgkmcnt(0)" ::: "memory");
        #pragma unroll
        for (int nt = 0; nt < 2; nt++)
            #pragma unroll
            for (int r = 0; r < 4; r++)
                hl[(kg * 4 + r) * 36 + nt * 16 + ur] = fmaxf(c1[nt][r], 0.f);
        #pragma unroll
        for (int q = 0; q < 4; q++) b0l[ur * 20 + kg * 4 + q] = p4[q] * inv;
        asm volatile("s_waitcnt lgkmcnt(0)" ::: "memory");
        half8 ah;
        {
            const float* hp = hl + ur * 36 + kg * 8;
            #pragma unroll
            for (int q = 0; q < 8; q++) ah[q] = (_Float16)hp[q];
        }
        floatx4 c20 = {0.f, 0.f, 0.f, 0.f};
        c20 = __builtin_amdgcn_mfma_f32_16x16x32_f16(ah, b2[0], c20, 0, 0, 0);
        floatx4 c21 = {bl2v, bl2v, bl2v, bl2v};
        c21 = __builtin_amdgcn_mfma_f32_16x16x32_f16(ah, b2[1], c21, 0, 0, 0);
        #pragma unroll
        for (int r = 0; r < 4; r++){
            int urow = kg * 4 + r;
            int ug = u0 + urow;
            if (ug < NU){
                hu2e[(size_t)ug * 16 + ur] = (_Float16)c20[r];
                ou[(size_t)ug * 16 + ur]   = (_Float16)(c21[r] + b0l[urow * 20 + ur]);
            }
        }
    }
}

// ---------------- layer 2 course side (fp16 hu2e gather, 4 chains) ----------------

__global__ __launch_bounds__(256) void k_course_l2(
    const int* __restrict__ off_c, const int* __restrict__ csr_c,
    const _Float16* __restrict__ hu2e, const float* __restrict__ bl2,
    const float* __restrict__ hcWr, float* __restrict__ oc, int NC)
{
    __shared__ float part[256];
    int t = threadIdx.x; int el = t >> 4, f = t & 15;
    for (int c = blockIdx.x; c < NC; c += gridDim.x){
        int lo = off_c[c], hi = off_c[c + 1];
        float acc = 0.f;
        int j = lo + el;
        for (; j + 48 < hi; j += 64){
            acc += (float)hu2e[(size_t)csr_c[j] * 16 + f] + (float)hu2e[(size_t)csr_c[j + 16] * 16 + f]
                 + (float)hu2e[(size_t)csr_c[j + 32] * 16 + f] + (float)hu2e[(size_t)csr_c[j + 48] * 16 + f];
        }
        for (; j < hi; j += 16) acc += (float)hu2e[(size_t)csr_c[j] * 16 + f];
        part[t] = acc; __syncthreads();
        if (el == 0){
            float s = part[f];
            #pragma unroll
            for (int k = 1; k < 16; k++) s += part[k * 16 + f];
            oc[c * 16 + f] = s / (float)imax(hi - lo, 1) + bl2[f] + hcWr[c * 16 + f];
        }
        __syncthreads();
    }
}

// ---------------- decode (fp16 ou gather) ----------------

__global__ void k_decode(const int* __restrict__ ls, const int* __restrict__ ld,
                         const _Float16* __restrict__ ou, const float* __restrict__ oc,
                         float* __restrict__ out, int L){
    int gt = blockIdx.x * blockDim.x + threadIdx.x;
    int l = gt >> 2, q = gt & 3;
    if (l >= L) return;
    int a = ls[l], b = ld[l];
    half4 va = *(const half4*)(ou + (size_t)a * 16 + q * 4);
    float4 vb = ((const float4*)(oc + (size_t)b * 16))[q];
    float s = (float)va[0] * vb.x + (float)va[1] * vb.y + (float)va[2] * vb.z + (float)va[3] * vb.w;
    s += __shfl_xor(s, 1);
    s += __shfl_xor(s, 2);
    if (q == 0) out[l] = s;
}

// ---------------- launcher ----------------

extern "C" void kernel_launch(void* const* d_in, const int* in_sizes, int n_in,
                              void* d_out, int out_size, void* d_ws, size_t ws_size,
                              hipStream_t stream)
{
    const float* user_x       = (const float*)d_in[0];
    const float* course_x     = (const float*)d_in[1];
    const float* user_embed   = (const float*)d_in[2];
    const float* course_embed = (const float*)d_in[3];
    const float* Wu = (const float*)d_in[4];
    const float* bu = (const float*)d_in[5];
    const float* Wc = (const float*)d_in[6];
    const float* bc = (const float*)d_in[7];
    const float* c1e_Wl = (const float*)d_in[8];
    const float* c1e_bl = (const float*)d_in[9];
    const float* c1e_Wr = (const float*)d_in[10];
    const float* c1r_Wl = (const float*)d_in[11];
    const float* c1r_bl = (const float*)d_in[12];
    const float* c1r_Wr = (const float*)d_in[13];
    const float* c2e_Wl = (const float*)d_in[14];
    const float* c2e_bl = (const float*)d_in[15];
    const float* c2e_Wr = (const float*)d_in[16];
    const float* c2r_Wl = (const float*)d_in[17];
    const float* c2r_bl = (const float*)d_in[18];
    const float* c2r_Wr = (const float*)d_in[19];
    const int* uidx      = (const int*)d_in[20];
    const int* cidx      = (const int*)d_in[21];
    const int* edge_src  = (const int*)d_in[22];
    const int* edge_dst  = (const int*)d_in[23];
    const int* label_src = (const int*)d_in[24];
    const int* label_dst = (const int*)d_in[25];
    const int NU = in_sizes[20], NC = in_sizes[21], E = in_sizes[22], L = in_sizes[24];
    const int NBC = (NC + (1 << CSH) - 1) >> CSH;
    const int NBU = (NU + (1 << USH) - 1) >> USH;

    char* ws = (char*)d_ws;
    size_t woff = 0;
    auto alloc = [&](size_t bytes) -> char* {
        char* p = ws + woff;
        woff = (woff + bytes + 255) & ~(size_t)255;
        return p;
    };
    int*   off_u = (int*)  alloc((size_t)(NU + 1) * 4);
    int*   off_c = (int*)  alloc((size_t)(NC + 1) * 4);
    int*   csr_c = (int*)  alloc((size_t)E * 4);
    int*   csr_u = (int*)  alloc((size_t)E * 4);
    float* xc    = (float*)alloc((size_t)NC * 32 * 4);
    _Float16* xc16 = (_Float16*)alloc((size_t)NC * 32 * 2);
    _Float16* hc2r16 = (_Float16*)alloc((size_t)NC * 16 * 2);
    float* hcWr  = (float*)alloc((size_t)NC * 16 * 4);
    _Float16* hu2e = (_Float16*)alloc((size_t)NU * 16 * 2);  // 16MB; binned_c aliases (E*4 = 8MB)
    _Float16* ou   = (_Float16*)alloc((size_t)NU * 16 * 2);  // 16MB; binned_u aliases (E*4 = 8MB)
    float* occ   = (float*)alloc((size_t)NC * 16 * 4);
    _Float16* xu16 = (_Float16*)alloc((size_t)NU * 32 * 2);
    _Float16* wB1a = (_Float16*)alloc(1024 * 2);
    _Float16* wB1b = (_Float16*)alloc(1024 * 2);
    _Float16* wB2  = (_Float16*)alloc(1024 * 2);
    float* whb     = (float*)alloc(32 * 4);
    int*   cnt_c  = (int*) alloc(MAXBIN * 4);
    int*   cnt_u  = (int*) alloc(MAXBIN * 4);
    int*   base_c = (int*) alloc(MAXBIN * 4);
    int*   base_u = (int*) alloc(MAXBIN * 4);
    int*   cur_c  = (int*) alloc(MAXBIN * 4);
    int*   cur_u  = (int*) alloc(MAXBIN * 4);
    unsigned* binned_c = (unsigned*)hu2e;
    unsigned* binned_u = (unsigned*)ou;
    (void)ws_size; (void)n_in; (void)out_size;

    int chunks = (E + 2047) / 2048;
    int featblocks = (NU + NC * 32 + 255) / 256;

    hipMemsetAsync(cnt_c, 0, 2 * MAXBIN * 4, stream);   // cnt_c and cnt_u are adjacent
    k_p0feat<<<chunks + featblocks, 256, 0, stream>>>(edge_src, edge_dst, cnt_c, cnt_u, E, NBC, NBU, chunks,
                                                      user_embed, uidx, user_x, xu16, NU,
                                                      course_x, course_embed, cidx, Wc, bc, xc, xc16, NC);
    k_misc<<<2, 256, 0, stream>>>(cnt_c, cnt_u, base_c, cur_c, base_u, cur_u, off_c, off_u,
                                  NC, NU, NBC, NBU, E,
                                  c1r_Wl, c1r_bl, c1r_Wr, Wu, bu, c2e_Wl, c2r_Wr, wB1a, wB1b, wB2, whb);
    k_phase1<<<chunks, 256, 0, stream>>>(edge_src, edge_dst, cur_c, cur_u, binned_c, binned_u, E, NBC, NBU);
    k_p2<<<NBC + NBU, 1024, 0, stream>>>(binned_c, binned_u, cnt_c, base_c, cnt_u, base_u,
                                         off_c, csr_c, off_u, csr_u, NC, NU, NBC);
    k_course_l1<<<2048, 256, 0, stream>>>(off_c, csr_c, xu16, Wu, bu,
                                          c1e_Wl, c1e_bl, c1e_Wr, c2r_Wl, c2e_Wr, xc, hc2r16, hcWr, NC);
    k_user_mfma<<<2048, 256, 0, stream>>>(off_u, csr_u, xc16, hc2r16, xu16,
                                          wB1a, wB1b, wB2, whb, c2r_bl, hu2e, ou, NU);
    k_course_l2<<<2048, 256, 0, stream>>>(off_c, csr_c, hu2e, c2e_bl, hcWr, occ, NC);
    k_decode<<<(unsigned)(((size_t)L * 4 + 255) / 256), 256, 0, stream>>>(label_src, label_dst, ou, occ, (float*)d_out, L);
}